// Round 2
// baseline (239.845 us; speedup 1.0000x reference)
//
#include <hip/hip_runtime.h>
#include <math.h>

// Problem constants (B, NP, NQ, D) = (4, 256, 256, 512)
#define BB   4
#define NP   256
#define NQ   256
#define DD   512
#define DD4  (DD / 4)

static constexpr float kScale = 1.0f / 22.627417f;  // 1/sqrt(512)

// ---------------------------------------------------------------------------
// scores[b,p,c] = dot(qmat[b,p,:], kmat[b,c,:]) * kScale  (c = 0..255)
// attn = softmax over c; logattn = log_softmax over c (optional).
// Block: 256 threads handles 8 consecutive p-rows of one batch.
// Grid: (NP/8, B).
// ---------------------------------------------------------------------------
__global__ __launch_bounds__(256) void scores_softmax_kernel(
    const float* __restrict__ qmat,     // [B, 256, D] rows
    const float* __restrict__ kmat,     // [B, 256, D] cols
    float* __restrict__ attn_out,       // [B, 256, 256]
    float* __restrict__ logattn_out)    // [B, 256, 256] or nullptr
{
    const int b  = blockIdx.y;
    const int p0 = blockIdx.x * 8;
    const int t  = threadIdx.x;

    __shared__ float qs[8][DD];    // 16 KiB: 8 q-rows
    __shared__ float ss[8][256];   // 8 KiB: scaled scores

    // Cooperatively load 8 q-rows (8*512 floats = 1024 float4; 4 per thread).
    {
        const float4* qrow = (const float4*)(qmat + ((size_t)b * 256 + p0) * DD);
        float4* qs4 = (float4*)&qs[0][0];
        #pragma unroll
        for (int i = 0; i < 4; ++i) qs4[t + i * 256] = qrow[t + i * 256];
    }
    __syncthreads();

    // Thread t: dot of each of the 8 q-rows with k-row t.
    float acc[8] = {0.f, 0.f, 0.f, 0.f, 0.f, 0.f, 0.f, 0.f};
    {
        const float4* krow = (const float4*)(kmat + ((size_t)b * 256 + t) * DD);
        for (int d4 = 0; d4 < DD4; ++d4) {
            float4 kv = krow[d4];
            #pragma unroll
            for (int r = 0; r < 8; ++r) {
                float4 qv = ((const float4*)qs[r])[d4];
                acc[r] += qv.x * kv.x + qv.y * kv.y + qv.z * kv.z + qv.w * kv.w;
            }
        }
    }
    #pragma unroll
    for (int r = 0; r < 8; ++r) ss[r][t] = acc[r] * kScale;
    __syncthreads();

    // Softmax: 32 threads per row, 8 elements each. Row r = t>>5, lane-group
    // g = t&31 (xor offsets <=16 stay within the 32-lane half-wave).
    const int r = t >> 5;
    const int g = t & 31;
    float vals[8];
    float m = -INFINITY;
    #pragma unroll
    for (int j = 0; j < 8; ++j) {
        vals[j] = ss[r][g * 8 + j];
        m = fmaxf(m, vals[j]);
    }
    #pragma unroll
    for (int off = 16; off >= 1; off >>= 1) m = fmaxf(m, __shfl_xor(m, off, 64));

    float s = 0.f;
    #pragma unroll
    for (int j = 0; j < 8; ++j) {
        vals[j] = expf(vals[j] - m);
        s += vals[j];
    }
    #pragma unroll
    for (int off = 16; off >= 1; off >>= 1) s += __shfl_xor(s, off, 64);

    const float inv = 1.0f / s;
    const float lse = logf(s);

    const size_t base = ((size_t)b * 256 + (p0 + r)) * 256 + g * 8;
    #pragma unroll
    for (int j = 0; j < 8; ++j) attn_out[base + j] = vals[j] * inv;
    if (logattn_out != nullptr) {
        #pragma unroll
        for (int j = 0; j < 8; ++j)
            logattn_out[base + j] = (ss[r][g * 8 + j] - m) - lse;
    }
}

// ---------------------------------------------------------------------------
// output[b,n,p,d] = gate[b,n,p] * (v[b,p,d] + query_v[b,n,d])
// Grid-stride over float4 elements; lane i writes element i (coalesced).
// ---------------------------------------------------------------------------
__global__ __launch_bounds__(256) void gate_combine_kernel(
    const float* __restrict__ gate,   // [B, NQ, NP]
    const float4* __restrict__ v4,    // [B, NP, D/4]
    const float4* __restrict__ qv4,   // [B, NQ, D/4]
    float4* __restrict__ out4)        // [B, NQ, NP, D/4]
{
    const size_t total  = (size_t)BB * NQ * NP * DD4;  // 33,554,432
    const size_t stride = (size_t)gridDim.x * blockDim.x;
    for (size_t i = (size_t)blockIdx.x * blockDim.x + threadIdx.x;
         i < total; i += stride) {
        const int d4 = (int)(i & (DD4 - 1));
        size_t rest  = i >> 7;                 // DD4 = 128
        const int p  = (int)(rest & (NP - 1)); rest >>= 8;
        const int n  = (int)(rest & (NQ - 1));
        const int b  = (int)(rest >> 8);

        const float gpn = gate[((size_t)b * NQ + n) * NP + p];
        const float4 vv = v4[((size_t)b * NP + p) * DD4 + d4];
        const float4 qv = qv4[((size_t)b * NQ + n) * DD4 + d4];
        float4 o;
        o.x = gpn * (vv.x + qv.x);
        o.y = gpn * (vv.y + qv.y);
        o.z = gpn * (vv.z + qv.z);
        o.w = gpn * (vv.w + qv.w);
        out4[i] = o;
    }
}

extern "C" void kernel_launch(void* const* d_in, const int* in_sizes, int n_in,
                              void* d_out, int out_size, void* d_ws, size_t ws_size,
                              hipStream_t stream) {
    // setup_inputs order: q, k, v, query(unused), query_q, query_k, query_v
    const float* q  = (const float*)d_in[0];
    const float* k  = (const float*)d_in[1];
    const float* v  = (const float*)d_in[2];
    const float* qq = (const float*)d_in[4];
    const float* qk = (const float*)d_in[5];
    const float* qv = (const float*)d_in[6];

    float* out = (float*)d_out;
    const size_t out_elems = (size_t)BB * NQ * NP * DD;          // 134,217,728
    float* attn_out    = out + out_elems;                         // [B,NP,NQ]
    float* logattn_out = attn_out + (size_t)BB * NP * NQ;         // [B,NP,NQ]

    dim3 sgrid(NP / 8, BB);

    // 1) query_attn = softmax(query_q . query_k^T / T) -> stash in attn slot.
    scores_softmax_kernel<<<sgrid, 256, 0, stream>>>(qq, qk, attn_out, nullptr);

    // 2) big gated-combine write (reads the stashed gate).
    gate_combine_kernel<<<4096, 256, 0, stream>>>(
        attn_out, (const float4*)v, (const float4*)qv, (float4*)out);

    // 3) real attn / log_attn overwrite the stash slot.
    scores_softmax_kernel<<<sgrid, 256, 0, stream>>>(q, k, attn_out, logattn_out);
}

// Round 3
// 151.810 us; speedup vs baseline: 1.5799x; 1.5799x over previous
//
#include <hip/hip_runtime.h>
#include <math.h>

// Problem constants (B, NP, NQ, D) = (4, 256, 256, 512)
#define BB   4
#define NP   256
#define NQ   256
#define DD   512
#define DD4  (DD / 4)

typedef float f32x4 __attribute__((ext_vector_type(4)));

static constexpr float kScale = 1.0f / 22.627417f;  // 1/sqrt(512)

// ---------------------------------------------------------------------------
// scores[b,p,c] = dot(qmat[b,p,:], kmat[b,c,:]) * kScale, softmax over c.
// Block: 256 threads = 4 rows of one batch; thread t owns column t.
// q reads are wave-uniform (scalar-promoted); k reads stream per-lane rows.
// Grid: (NP/4, B) = (64, 4) = 256 blocks.
// ---------------------------------------------------------------------------
__global__ __launch_bounds__(256) void scores_softmax4_kernel(
    const float* __restrict__ qmat,     // [B, NP, D]
    const float* __restrict__ kmat,     // [B, NQ(=256), D]
    float* __restrict__ attn_out,       // [B, NP, 256]
    float* __restrict__ logattn_out)    // [B, NP, 256] or nullptr
{
    const int b  = blockIdx.y;
    const int p0 = blockIdx.x * 4;
    const int t  = threadIdx.x;

    const f32x4* krow = (const f32x4*)(kmat + ((size_t)b * 256 + t) * DD);
    const float* qb   = qmat + ((size_t)b * NP + p0) * DD;   // 4 q-rows, uniform

    float acc[4] = {0.f, 0.f, 0.f, 0.f};
    #pragma unroll 8
    for (int d4 = 0; d4 < DD4; ++d4) {
        const f32x4 kv = krow[d4];
        #pragma unroll
        for (int r = 0; r < 4; ++r) {
            const float* qr = qb + r * DD + d4 * 4;   // wave-uniform address
            acc[r] += qr[0] * kv.x + qr[1] * kv.y + qr[2] * kv.z + qr[3] * kv.w;
        }
    }

    __shared__ __align__(16) float ss[4][256];
    #pragma unroll
    for (int r = 0; r < 4; ++r) ss[r][t] = acc[r] * kScale;
    __syncthreads();

    // Wave r (= t>>6) reduces row r; lane g owns 4 consecutive columns.
    const int r = t >> 6;
    const int g = t & 63;
    const f32x4 sv = ((const f32x4*)ss[r])[g];   // raw scaled scores

    float m = fmaxf(fmaxf(sv.x, sv.y), fmaxf(sv.z, sv.w));
    #pragma unroll
    for (int off = 32; off >= 1; off >>= 1) m = fmaxf(m, __shfl_xor(m, off, 64));

    f32x4 ev;
    ev.x = expf(sv.x - m); ev.y = expf(sv.y - m);
    ev.z = expf(sv.z - m); ev.w = expf(sv.w - m);
    float s = ev.x + ev.y + ev.z + ev.w;
    #pragma unroll
    for (int off = 32; off >= 1; off >>= 1) s += __shfl_xor(s, off, 64);

    const float inv = 1.0f / s;
    const float lse = logf(s);

    const size_t base = ((size_t)b * NP + (p0 + r)) * 256;
    ((f32x4*)(attn_out + base))[g] = ev * inv;
    if (logattn_out != nullptr) {
        f32x4 lg;
        lg.x = (sv.x - m) - lse; lg.y = (sv.y - m) - lse;
        lg.z = (sv.z - m) - lse; lg.w = (sv.w - m) - lse;
        ((f32x4*)(logattn_out + base))[g] = lg;
    }
}

// ---------------------------------------------------------------------------
// output[b,n,p,d] = gate[b,n,p] * (v[b,p,d] + query_v[b,n,d])
// Block = one (b,n) pair, 256 threads: thread t owns d4 = t&127, row-parity
// po = t>>7. query_v float4 lives in a register for the whole kernel; gate
// loads are wave-uniform; v loads coalesced + L2-resident; stores contiguous
// nontemporal float4. Grid: B*NQ = 1024 blocks.
// ---------------------------------------------------------------------------
__global__ __launch_bounds__(256) void gate_combine2_kernel(
    const float* __restrict__ gate,   // [B, NQ, NP]
    const f32x4* __restrict__ v4,     // [B, NP, DD4]
    const f32x4* __restrict__ qv4,    // [B, NQ, DD4]
    f32x4* __restrict__ out4)         // [B, NQ, NP, DD4]
{
    const int bn = blockIdx.x;
    const int b  = bn >> 8;
    const int n  = bn & (NQ - 1);
    const int t  = threadIdx.x;
    const int d4 = t & (DD4 - 1);
    const int po = t >> 7;            // 0 or 1

    const f32x4 qvr = qv4[((size_t)b * NQ + n) * DD4 + d4];
    const float* grow = gate + ((size_t)b * NQ + n) * NP;
    const f32x4* vcol = v4 + (size_t)b * NP * DD4 + d4;
    f32x4* ocol = out4 + ((size_t)b * NQ + n) * ((size_t)NP * DD4) + d4;

    #pragma unroll 4
    for (int p = po; p < NP; p += 2) {
        const float gpn = grow[p];                   // wave-uniform
        const f32x4 vv  = vcol[(size_t)p * DD4];
        const f32x4 o   = (vv + qvr) * gpn;
        __builtin_nontemporal_store(o, ocol + (size_t)p * DD4);
    }
}

extern "C" void kernel_launch(void* const* d_in, const int* in_sizes, int n_in,
                              void* d_out, int out_size, void* d_ws, size_t ws_size,
                              hipStream_t stream) {
    // setup_inputs order: q, k, v, query(unused), query_q, query_k, query_v
    const float* q  = (const float*)d_in[0];
    const float* k  = (const float*)d_in[1];
    const float* v  = (const float*)d_in[2];
    const float* qq = (const float*)d_in[4];
    const float* qk = (const float*)d_in[5];
    const float* qv = (const float*)d_in[6];

    float* out = (float*)d_out;
    const size_t out_elems = (size_t)BB * NQ * NP * DD;          // 134,217,728
    float* attn_out    = out + out_elems;                         // [B,NP,256]
    float* logattn_out = attn_out + (size_t)BB * NP * 256;        // [B,NP,256]

    dim3 sgrid(NP / 4, BB);   // 256 blocks

    // 1) query_attn = softmax(query_q . query_k^T / T) -> stash in attn slot.
    scores_softmax4_kernel<<<sgrid, 256, 0, stream>>>(qq, qk, attn_out, nullptr);

    // 2) big gated-combine write (reads the stashed gate).
    gate_combine2_kernel<<<BB * NQ, 256, 0, stream>>>(
        attn_out, (const f32x4*)v, (const f32x4*)qv, (f32x4*)out);

    // 3) real attn / log_attn overwrite the stash slot.
    scores_softmax4_kernel<<<sgrid, 256, 0, stream>>>(q, k, attn_out, logattn_out);
}

// Round 4
// 131.938 us; speedup vs baseline: 1.8179x; 1.1506x over previous
//
#include <hip/hip_runtime.h>
#include <math.h>

// Problem constants (B, NP, NQ, D) = (4, 256, 256, 512)
#define BB   4
#define NP   256
#define NQ   256
#define DD   512
#define DD4  (DD / 4)

typedef float f32x4 __attribute__((ext_vector_type(4)));

static constexpr float kScale = 1.0f / 22.627417f;  // 1/sqrt(512)

// ---------------------------------------------------------------------------
// Fused kernel, grid.x = 1280:
//  blocks [0, 1024):   one (b,n) each. Compute query_attn[b,n,:] in-block
//                      (dot512 per thread + block softmax -> LDS), then the
//                      big gated-combine streaming write of out[b,n,:,:].
//  blocks [1024,1280): 4 p-rows each of attn/log_attn = softmax(q.k^T/T).
// ---------------------------------------------------------------------------
__global__ __launch_bounds__(256) void fused_qgsa_kernel(
    const float* __restrict__ q,     // [B, NP, D]
    const float* __restrict__ k,     // [B, NP, D]
    const f32x4* __restrict__ v4,    // [B, NP, DD4]
    const float* __restrict__ qq,    // [B, NQ, D]
    const float* __restrict__ qk,    // [B, NP, D]
    const f32x4* __restrict__ qv4,   // [B, NQ, DD4]
    f32x4* __restrict__ out4,        // [B, NQ, NP, DD4]
    float* __restrict__ attn_out,    // [B, NP, NP]
    float* __restrict__ logattn_out) // [B, NP, NP]
{
    __shared__ __align__(16) float smem[4 * 256];
    __shared__ float red[8];
    const int t = threadIdx.x;

    if (blockIdx.x < (unsigned)(BB * NQ)) {
        // ---------------- type A: gate + streaming write ----------------
        const int bn = blockIdx.x;
        const int b  = bn >> 8;
        const int n  = bn & (NQ - 1);
        const int w  = t >> 6;
        const int l  = t & 63;

        // q_scores[b,n,t] = dot(qq[b,n,:], qk[b,t,:]) * kScale
        float val;
        {
            const f32x4* krow = (const f32x4*)(qk + ((size_t)b * NP + t) * DD);
            const float* qrow = qq + ((size_t)b * NQ + n) * DD;  // wave-uniform
            float acc = 0.f;
            #pragma unroll 8
            for (int d4 = 0; d4 < DD4; ++d4) {
                const f32x4 kv = krow[d4];
                const float* qr = qrow + d4 * 4;
                acc += qr[0] * kv.x + qr[1] * kv.y + qr[2] * kv.z + qr[3] * kv.w;
            }
            val = acc * kScale;
        }

        // Block softmax over the 256 values (one per thread) -> gate in LDS.
        float m = val;
        #pragma unroll
        for (int off = 32; off >= 1; off >>= 1) m = fmaxf(m, __shfl_xor(m, off, 64));
        if (l == 0) red[w] = m;
        __syncthreads();
        m = fmaxf(fmaxf(red[0], red[1]), fmaxf(red[2], red[3]));

        const float e = expf(val - m);
        float s = e;
        #pragma unroll
        for (int off = 32; off >= 1; off >>= 1) s += __shfl_xor(s, off, 64);
        if (l == 0) red[4 + w] = s;
        __syncthreads();
        s = (red[4] + red[5]) + (red[6] + red[7]);

        smem[t] = e / s;          // gate[b,n,t]
        __syncthreads();

        // out[b,n,p,:] = gate[p] * (v[b,p,:] + qv[b,n,:])
        const int d4 = t & (DD4 - 1);
        const int po = t >> 7;    // 0 or 1
        const f32x4 qvr = qv4[((size_t)b * NQ + n) * DD4 + d4];
        const f32x4* vcol = v4 + (size_t)b * NP * DD4 + d4;
        f32x4* ocol = out4 + ((size_t)b * NQ + n) * ((size_t)NP * DD4) + d4;

        #pragma unroll 4
        for (int p = po; p < NP; p += 2) {
            const float gpn = smem[p];                 // LDS broadcast
            const f32x4 vv  = vcol[(size_t)p * DD4];
            const f32x4 o   = (vv + qvr) * gpn;
            __builtin_nontemporal_store(o, ocol + (size_t)p * DD4);
        }
    } else {
        // ---------------- type B: attn / log_attn softmax ----------------
        const int idx = blockIdx.x - BB * NQ;          // 0..255
        const int b   = idx >> 6;
        const int p0  = (idx & 63) * 4;

        const f32x4* krow = (const f32x4*)(k + ((size_t)b * NP + t) * DD);
        const float* qb   = q + ((size_t)b * NP + p0) * DD;   // wave-uniform

        float acc[4] = {0.f, 0.f, 0.f, 0.f};
        #pragma unroll 8
        for (int d4 = 0; d4 < DD4; ++d4) {
            const f32x4 kv = krow[d4];
            #pragma unroll
            for (int r = 0; r < 4; ++r) {
                const float* qr = qb + r * DD + d4 * 4;
                acc[r] += qr[0] * kv.x + qr[1] * kv.y + qr[2] * kv.z + qr[3] * kv.w;
            }
        }

        float (*ss)[256] = (float (*)[256])smem;
        #pragma unroll
        for (int r = 0; r < 4; ++r) ss[r][t] = acc[r] * kScale;
        __syncthreads();

        // Wave r (= t>>6) reduces row r; lane g owns 4 consecutive columns.
        const int r = t >> 6;
        const int g = t & 63;
        const f32x4 sv = ((const f32x4*)ss[r])[g];

        float m = fmaxf(fmaxf(sv.x, sv.y), fmaxf(sv.z, sv.w));
        #pragma unroll
        for (int off = 32; off >= 1; off >>= 1) m = fmaxf(m, __shfl_xor(m, off, 64));

        f32x4 ev;
        ev.x = expf(sv.x - m); ev.y = expf(sv.y - m);
        ev.z = expf(sv.z - m); ev.w = expf(sv.w - m);
        float s = (ev.x + ev.y) + (ev.z + ev.w);
        #pragma unroll
        for (int off = 32; off >= 1; off >>= 1) s += __shfl_xor(s, off, 64);

        const float inv = 1.0f / s;
        const float lse = logf(s);

        const size_t base = ((size_t)b * NP + (p0 + r)) * 256;
        ((f32x4*)(attn_out + base))[g] = ev * inv;
        f32x4 lg;
        lg.x = (sv.x - m) - lse; lg.y = (sv.y - m) - lse;
        lg.z = (sv.z - m) - lse; lg.w = (sv.w - m) - lse;
        ((f32x4*)(logattn_out + base))[g] = lg;
    }
}

extern "C" void kernel_launch(void* const* d_in, const int* in_sizes, int n_in,
                              void* d_out, int out_size, void* d_ws, size_t ws_size,
                              hipStream_t stream) {
    // setup_inputs order: q, k, v, query(unused), query_q, query_k, query_v
    const float* q  = (const float*)d_in[0];
    const float* k  = (const float*)d_in[1];
    const float* v  = (const float*)d_in[2];
    const float* qq = (const float*)d_in[4];
    const float* qk = (const float*)d_in[5];
    const float* qv = (const float*)d_in[6];

    float* out = (float*)d_out;
    const size_t out_elems = (size_t)BB * NQ * NP * DD;          // 134,217,728
    float* attn_out    = out + out_elems;                         // [B,NP,256]
    float* logattn_out = attn_out + (size_t)BB * NP * 256;        // [B,NP,256]

    fused_qgsa_kernel<<<BB * NQ + 256, 256, 0, stream>>>(
        q, k, (const f32x4*)v, qq, qk, (const f32x4*)qv,
        (f32x4*)out, attn_out, logattn_out);
}